// Round 7
// baseline (459.786 us; speedup 1.0000x reference)
//
#include <hip/hip_runtime.h>

#define CHUNK 2048

// Fused: embed blocks [0,embed_blocks) + per-chunk bucket histogram blocks.
// pcount is stored TRANSPOSED [bucket][chunk] so colscan's read is coalesced.
__global__ __launch_bounds__(256) void embed_count_kernel(
    const int* __restrict__ x, const float* __restrict__ emb, float* __restrict__ h0,
    const int* __restrict__ ei, int* __restrict__ pcount,
    int n_nodes, int n_edges, int n_bkt, int n_chk, int embed_blocks)
{
    __shared__ int cnt[512];
    int t = threadIdx.x;
    if ((int)blockIdx.x < embed_blocks) {
        int tt = blockIdx.x * 256 + t;
        if (tt < n_nodes * 16) {
            int n = tt >> 4, q = tt & 15;
            int xv = x[n];
            float4 v = {0.f, 0.f, 0.f, 0.f};
            if (xv != 0) v = *(const float4*)(emb + (size_t)xv * 64 + q * 4);
            *(float4*)(h0 + (size_t)n * 64 + q * 4) = v;
        }
        return;
    }
    int jb = blockIdx.x - embed_blocks;
    for (int b = t; b < 512; b += 256) cnt[b] = 0;
    __syncthreads();
    int base = jb * CHUNK;
#pragma unroll
    for (int i = 0; i < CHUNK / 256; ++i) {
        int e = base + i * 256 + t;
        if (e < n_edges) atomicAdd(&cnt[ei[n_edges + e] >> 7], 1);
    }
    __syncthreads();
    for (int b = t; b < n_bkt; b += 256) pcount[b * n_chk + jb] = cnt[b];
}

// blocks [0,n_bkt): exclusive scan over chunk counts -> pre, totals.
// blocks [n_bkt, ...): per-graph bounds -> inv_cnt[g]; out[g] init to linb.
__global__ __launch_bounds__(256) void colscan_kernel(
    const int* __restrict__ pcount, int* __restrict__ pre,
    int* __restrict__ totals, int* __restrict__ rowstartR,
    const int* __restrict__ batch, const float* __restrict__ linb,
    float* __restrict__ inv_cnt, float* __restrict__ outg,
    int n_chk, int n_bkt, int n_edges, int n_nodes, int n_graphs)
{
    __shared__ int ps[256];
    int b = blockIdx.x, t = threadIdx.x;
    if (b >= n_bkt) {
        int g = (b - n_bkt) * 256 + t;
        if (g < n_graphs) {
            int lo = 0, hi = n_nodes;
            while (lo < hi) { int mid = (lo + hi) >> 1; if (batch[mid] < g) lo = mid + 1; else hi = mid; }
            int s = lo;
            lo = 0; hi = n_nodes;
            while (lo < hi) { int mid = (lo + hi) >> 1; if (batch[mid] < g + 1) lo = mid + 1; else hi = mid; }
            inv_cnt[g] = 1.f / (float)max(lo - s, 1);
            outg[2 * g + 0] = linb[0];
            outg[2 * g + 1] = linb[1];
        }
        return;
    }
    if (b == 0 && t == 0) rowstartR[4 * n_nodes] = n_edges;
    int v[4], s = 0;
#pragma unroll
    for (int i = 0; i < 4; ++i) {
        int jj = t * 4 + i;
        v[i] = (jj < n_chk) ? pcount[b * n_chk + jj] : 0;
        s += v[i];
    }
    ps[t] = s;
    __syncthreads();
    for (int o = 1; o < 256; o <<= 1) {
        int u = (t >= o) ? ps[t - o] : 0;
        __syncthreads();
        ps[t] += u;
        __syncthreads();
    }
    int run = (t > 0) ? ps[t - 1] : 0;
#pragma unroll
    for (int i = 0; i < 4; ++i) {
        int jj = t * 4 + i;
        if (jj < n_chk) pre[jj * n_bkt + b] = run;
        run += v[i];
    }
    if (t == 255) totals[b] = run;
}

// 611 blocks x 2048 edges; deterministic bases (local scan of totals + pre row),
// LDS fill atomics only. Block 0 publishes bucket_start for the sort.
__global__ __launch_bounds__(256) void scatter_kernel(
    const int* __restrict__ ei, const int* __restrict__ et,
    const int* __restrict__ pre, const int* __restrict__ totals,
    int* __restrict__ esort, int* __restrict__ bucket_start,
    int n_edges, int n_bkt)
{
    __shared__ int bs[512], fill2[512], ps[256];
    int t = threadIdx.x, j = blockIdx.x;
    int a0 = (2 * t < n_bkt) ? totals[2 * t] : 0;
    int a1 = (2 * t + 1 < n_bkt) ? totals[2 * t + 1] : 0;
    ps[t] = a0 + a1;
    __syncthreads();
    for (int o = 1; o < 256; o <<= 1) {
        int u = (t >= o) ? ps[t - o] : 0;
        __syncthreads();
        ps[t] += u;
        __syncthreads();
    }
    int basex = (t > 0) ? ps[t - 1] : 0;
    bs[2 * t] = basex;
    bs[2 * t + 1] = basex + a0;
    fill2[t] = 0; fill2[t + 256] = 0;
    __syncthreads();
    if (j == 0) {
        for (int b = t; b < n_bkt; b += 256) bucket_start[b] = bs[b];
        if (t == 0) bucket_start[n_bkt] = n_edges;
    }
    for (int b = t; b < n_bkt; b += 256) bs[b] += pre[j * n_bkt + b];
    __syncthreads();
    int base = j * CHUNK;
#pragma unroll
    for (int i = 0; i < CHUNK / 256; ++i) {
        int e = base + i * 256 + t;
        if (e < n_edges) {
            int s = ei[e], d = ei[n_edges + e], r = et[e];
            int b = d >> 7;
            int pos = bs[b] + atomicAdd(&fill2[b], 1);
            esort[pos] = s | (r << 16) | ((d & 127) << 18);
        }
    }
}

// one block per bucket: 512-bin counting sort (bin = dstlo*4 + r),
// emits rowstartR[dst*4 + r]. PING-PONG: esort_in -> esort_out.
__global__ __launch_bounds__(256) void bucket_sort_kernel(
    const int* __restrict__ bucket_start, const int* __restrict__ esort_in,
    int* __restrict__ esort_out, int* __restrict__ rowstartR, int n_nodes)
{
    __shared__ int cnt[512], off[512], fill[512], ps[256];
    int t = threadIdx.x, b = blockIdx.x;
    int s = bucket_start[b], e = bucket_start[b + 1];
    cnt[t] = 0; cnt[t + 256] = 0; fill[t] = 0; fill[t + 256] = 0;
    __syncthreads();
    for (int i = s + t; i < e; i += 256)
        atomicAdd(&cnt[(esort_in[i] >> 16) & 0x1FF], 1);
    __syncthreads();
    int a0 = cnt[2 * t], a1 = cnt[2 * t + 1];
    ps[t] = a0 + a1;
    __syncthreads();
    for (int o = 1; o < 256; o <<= 1) {
        int v = (t >= o) ? ps[t - o] : 0;
        __syncthreads();
        ps[t] += v;
        __syncthreads();
    }
    int basex = (t > 0) ? ps[t - 1] : 0;
    off[2 * t] = basex;
    off[2 * t + 1] = basex + a0;
    __syncthreads();
    int d0 = b * 128 + (2 * t >> 2);
    if (d0 < n_nodes) rowstartR[b * 512 + 2 * t] = s + off[2 * t];
    int d1 = b * 128 + ((2 * t + 1) >> 2);
    if (d1 < n_nodes) rowstartR[b * 512 + 2 * t + 1] = s + off[2 * t + 1];
    __syncthreads();
    for (int i = s + t; i < e; i += 256) {
        int p = esort_in[i];
        int bin = (p >> 16) & 0x1FF;
        int pos = s + off[bin] + atomicAdd(&fill[bin], 1);
        esort_out[pos] = p;
    }
}

// one wave per dst. R0's proven version (44.2 us): 4-wide window per quarter,
// plain cached esort loads, 3-way cndmask decode.
__global__ __launch_bounds__(256) void agg_kernel(
    const float* __restrict__ hin, const int* __restrict__ rowstartR,
    const int* __restrict__ esort, float* __restrict__ means, int n_nodes)
{
    int wid = (blockIdx.x * 256 + threadIdx.x) >> 6;
    int lane = threadIdx.x & 63;
    if (wid >= n_nodes) return;
    int q = lane >> 4;
    int c = lane & 15;
    int4 rs = *(const int4*)(rowstartR + wid * 4);
    int s = rs.x, e = rs.w;

    float4 a0 = {0.f,0.f,0.f,0.f}, a1 = {0.f,0.f,0.f,0.f}, a2 = {0.f,0.f,0.f,0.f};

    int i = s + 4 * q;
    for (; i + 4 <= e; i += 16) {
        int p0 = esort[i], p1 = esort[i + 1], p2 = esort[i + 2], p3 = esort[i + 3];
        float4 v0 = *(const float4*)(hin + (size_t)(p0 & 0xFFFF) * 64 + c * 4);
        float4 v1 = *(const float4*)(hin + (size_t)(p1 & 0xFFFF) * 64 + c * 4);
        float4 v2 = *(const float4*)(hin + (size_t)(p2 & 0xFFFF) * 64 + c * 4);
        float4 v3 = *(const float4*)(hin + (size_t)(p3 & 0xFFFF) * 64 + c * 4);
#pragma unroll
        for (int m = 0; m < 4; ++m) {
            int p = m == 0 ? p0 : m == 1 ? p1 : m == 2 ? p2 : p3;
            float4 v = m == 0 ? v0 : m == 1 ? v1 : m == 2 ? v2 : v3;
            int r = (p >> 16) & 3;
            float m0 = (r == 0) ? 1.f : 0.f;
            float m1 = (r == 1) ? 1.f : 0.f;
            float m2 = (r == 2) ? 1.f : 0.f;
            a0.x = fmaf(m0, v.x, a0.x); a0.y = fmaf(m0, v.y, a0.y);
            a0.z = fmaf(m0, v.z, a0.z); a0.w = fmaf(m0, v.w, a0.w);
            a1.x = fmaf(m1, v.x, a1.x); a1.y = fmaf(m1, v.y, a1.y);
            a1.z = fmaf(m1, v.z, a1.z); a1.w = fmaf(m1, v.w, a1.w);
            a2.x = fmaf(m2, v.x, a2.x); a2.y = fmaf(m2, v.y, a2.y);
            a2.z = fmaf(m2, v.z, a2.z); a2.w = fmaf(m2, v.w, a2.w);
        }
    }
#pragma unroll
    for (int m = 0; m < 3; ++m) {
        int ii = i + m;
        if (ii < e) {
            int p = esort[ii];
            float4 v = *(const float4*)(hin + (size_t)(p & 0xFFFF) * 64 + c * 4);
            int r = (p >> 16) & 3;
            float m0 = (r == 0) ? 1.f : 0.f;
            float m1 = (r == 1) ? 1.f : 0.f;
            float m2 = (r == 2) ? 1.f : 0.f;
            a0.x = fmaf(m0, v.x, a0.x); a0.y = fmaf(m0, v.y, a0.y);
            a0.z = fmaf(m0, v.z, a0.z); a0.w = fmaf(m0, v.w, a0.w);
            a1.x = fmaf(m1, v.x, a1.x); a1.y = fmaf(m1, v.y, a1.y);
            a1.z = fmaf(m1, v.z, a1.z); a1.w = fmaf(m1, v.w, a1.w);
            a2.x = fmaf(m2, v.x, a2.x); a2.y = fmaf(m2, v.y, a2.y);
            a2.z = fmaf(m2, v.z, a2.z); a2.w = fmaf(m2, v.w, a2.w);
        }
    }
#pragma unroll
    for (int off = 16; off < 64; off <<= 1) {
        a0.x += __shfl_xor(a0.x, off); a0.y += __shfl_xor(a0.y, off);
        a0.z += __shfl_xor(a0.z, off); a0.w += __shfl_xor(a0.w, off);
        a1.x += __shfl_xor(a1.x, off); a1.y += __shfl_xor(a1.y, off);
        a1.z += __shfl_xor(a1.z, off); a1.w += __shfl_xor(a1.w, off);
        a2.x += __shfl_xor(a2.x, off); a2.y += __shfl_xor(a2.y, off);
        a2.z += __shfl_xor(a2.z, off); a2.w += __shfl_xor(a2.w, off);
    }
    if (q < 3) {
        int cnt = (q == 0) ? (rs.y - rs.x) : (q == 1) ? (rs.z - rs.y) : (rs.w - rs.z);
        float4 a = (q == 0) ? a0 : (q == 1) ? a1 : a2;
        float inv = 1.f / (float)max(cnt, 1);
        float4 m = {a.x * inv, a.y * inv, a.z * inv, a.w * inv};
        *(float4*)(means + (size_t)wid * 192 + q * 64 + c * 4) = m;
    }
}

// ---------------------------------------------------------------------------
// transform, lane-per-node layout, v hoisted to VGPRs per phase.
// R6 post-mortem: W scalarized correctly (SGPR 112) but inner loop mixed
// ds_read_b128 (v) with the s_load W-stream. DS and SMEM share lgkmcnt and
// SMEM completes OUT OF ORDER -> every ds_read wait forces lgkmcnt(0), which
// drains the whole in-flight s_load pipeline: ~200cy L2 scalar latency eaten
// per k4 instead of pipelined (VALUBusy 23% = pure-FMA fraction; 77% stall).
// Fix: per phase, copy the lane's 64-float v-row LDS->VGPRs up front (16
// ds_read_b128, ONE lgkmcnt drain), then the FMA loop has only s_loads on
// lgkmcnt -> compiler pipelines 64 scalar row-loads against 32cy FMA/row.
// VGPR ~115 (vr 64 + acc 16 + stg 16), still 4 waves/SIMD.
// ---------------------------------------------------------------------------
__global__ __launch_bounds__(256, 4) void transform_kernel(
    const float* __restrict__ hin, const float* __restrict__ means,
    const float* __restrict__ wroot, const float* __restrict__ wrel,
    const float* __restrict__ bias, float* __restrict__ hout,
    const int* __restrict__ batch, const float* __restrict__ linw,
    const float* __restrict__ inv_cnt, float* __restrict__ outg,
    int n_nodes, int do_pool)
{
    __shared__ float smem[2][64 * 68];   // 2 x 17 KB v double-buffer (+reused epilogue)
    int t = threadIdx.x;
    int lane = t & 63;
    int wv = __builtin_amdgcn_readfirstlane(t >> 6);
    int j0 = wv * 16;
    int n0g = blockIdx.x * 64;

    int sn_ = t >> 4;            // staging: node sub-index within a round
    int sk  = (t & 15) * 4;      // staging: k offset (16 threads cover a row)

    float4 stg[4];
    // prologue: stage phase 0 (contiguous h slice) into smem[0]
#pragma unroll
    for (int r = 0; r < 4; ++r) {
        int node = r * 16 + sn_;
        int gn = min(n0g + node, n_nodes - 1);
        stg[r] = *(const float4*)(hin + (size_t)gn * 64 + sk);
    }
#pragma unroll
    for (int r = 0; r < 4; ++r) {
        int node = r * 16 + sn_;
        *(float4*)&smem[0][node * 68 + sk] = stg[r];
    }

    float acc[16];
#pragma unroll
    for (int i = 0; i < 16; ++i) acc[i] = bias[j0 + i];   // uniform -> s_load
    __syncthreads();

    for (int p = 0; p < 4; ++p) {
        if (p < 3) {   // issue next phase's global loads early (hide under FMAs)
#pragma unroll
            for (int r = 0; r < 4; ++r) {
                int node = r * 16 + sn_;
                int gn = min(n0g + node, n_nodes - 1);
                stg[r] = *(const float4*)(means + (size_t)gn * 192 + p * 64 + sk);
            }
        }
        // ---- v row LDS -> VGPRs, one lgkmcnt drain ----
        const float* lv = &smem[p & 1][lane * 68];
        float4 vr[16];
#pragma unroll
        for (int k4 = 0; k4 < 16; ++k4) vr[k4] = *(const float4*)(lv + k4 * 4);
        // ---- pure s_load + FMA stream (no DS ops on lgkmcnt) ----
        const float* wb = ((p == 0) ? wroot : (wrel + (size_t)(p - 1) * 4096)) + j0;
#pragma unroll
        for (int k4 = 0; k4 < 16; ++k4) {
#pragma unroll
            for (int kk = 0; kk < 4; ++kk) {
                float vk = kk == 0 ? vr[k4].x : kk == 1 ? vr[k4].y
                         : kk == 2 ? vr[k4].z : vr[k4].w;
                const float* wr = wb + (k4 * 4 + kk) * 64;   // uniform row -> s_load
#pragma unroll
                for (int i = 0; i < 16; ++i)
                    acc[i] = fmaf(vk, wr[i], acc[i]);
            }
        }
        if (p < 3) {
            __syncthreads();     // all waves done reading buf[(p+1)&1] (phase p-1)
#pragma unroll
            for (int r = 0; r < 4; ++r) {
                int node = r * 16 + sn_;
                *(float4*)&smem[(p + 1) & 1][node * 68 + sk] = stg[r];
            }
            __syncthreads();     // staged data visible before phase p+1 reads
        }
    }

    if (!do_pool) {
        __syncthreads();         // everyone past phase-2 reads -> smem[0] free
        float* osh = smem[0];    // [64][68] transpose turnaround
#pragma unroll
        for (int i4 = 0; i4 < 4; ++i4) {
            float4 r;
            r.x = fmaxf(acc[i4 * 4 + 0], 0.f);
            r.y = fmaxf(acc[i4 * 4 + 1], 0.f);
            r.z = fmaxf(acc[i4 * 4 + 2], 0.f);
            r.w = fmaxf(acc[i4 * 4 + 3], 0.f);
            *(float4*)&osh[lane * 68 + j0 + i4 * 4] = r;
        }
        __syncthreads();
#pragma unroll
        for (int r = 0; r < 4; ++r) {
            int node = r * 16 + sn_;
            int gn = n0g + node;
            if (gn < n_nodes)
                *(float4*)(hout + (size_t)gn * 64 + sk) =
                    *(const float4*)&osh[node * 68 + sk];
        }
    } else {
        float d0 = 0.f, d1 = 0.f;
#pragma unroll
        for (int i = 0; i < 16; ++i) {
            float rr = fmaxf(acc[i], 0.f);
            d0 = fmaf(rr, linw[(j0 + i) * 2 + 0], d0);   // uniform -> s_load
            d1 = fmaf(rr, linw[(j0 + i) * 2 + 1], d1);
        }
        __syncthreads();                 // compute buffers free
        float* wsum = smem[0];           // [4][64][2]
        float* gacc = smem[0] + 512;     // [64][2]
        wsum[(wv * 64 + lane) * 2 + 0] = d0;
        wsum[(wv * 64 + lane) * 2 + 1] = d1;
        if (t < 128) gacc[t] = 0.f;
        __syncthreads();
        int gmin = batch[min(n0g, n_nodes - 1)];
        if (t < 64) {
            int gn = n0g + t;
            if (gn < n_nodes) {
                float s0 = wsum[t * 2]     + wsum[128 + t * 2] +
                           wsum[256 + t * 2] + wsum[384 + t * 2];
                float s1 = wsum[t * 2 + 1]     + wsum[128 + t * 2 + 1] +
                           wsum[256 + t * 2 + 1] + wsum[384 + t * 2 + 1];
                int gg = batch[gn];
                float ic = inv_cnt[gg];
                int idx = gg - gmin;
                if (idx < 64) {
                    atomicAdd(&gacc[idx * 2 + 0], s0 * ic);
                    atomicAdd(&gacc[idx * 2 + 1], s1 * ic);
                } else {   // empty-graph gap fallback (practically never)
                    atomicAdd(&outg[2 * gg + 0], s0 * ic);
                    atomicAdd(&outg[2 * gg + 1], s1 * ic);
                }
            }
        }
        __syncthreads();
        if (t < 64) {
            float v0 = gacc[t * 2], v1 = gacc[t * 2 + 1];
            if (v0 != 0.f || v1 != 0.f) {
                atomicAdd(&outg[2 * (gmin + t) + 0], v0);
                atomicAdd(&outg[2 * (gmin + t) + 1], v1);
            }
        }
    }
}

extern "C" void kernel_launch(void* const* d_in, const int* in_sizes, int n_in,
                              void* d_out, int out_size, void* d_ws, size_t ws_size,
                              hipStream_t stream)
{
    const int*   x      = (const int*)d_in[0];
    const int*   ei     = (const int*)d_in[1];
    const int*   et     = (const int*)d_in[2];
    const int*   batch  = (const int*)d_in[3];
    const float* emb    = (const float*)d_in[4];
    const float* w1rel  = (const float*)d_in[5];
    const float* w1root = (const float*)d_in[6];
    const float* b1     = (const float*)d_in[7];
    const float* w2rel  = (const float*)d_in[8];
    const float* w2root = (const float*)d_in[9];
    const float* b2     = (const float*)d_in[10];
    const float* linw   = (const float*)d_in[11];
    const float* linb   = (const float*)d_in[12];
    float* out = (float*)d_out;

    const int N = in_sizes[0];            // 50000
    const int E = in_sizes[2];            // 1250000
    const int G = out_size / 2;           // 512
    const int NBKT = (N + 127) >> 7;      // 391
    const int NCHK = (E + CHUNK - 1) / CHUNK;  // 611

    float* hA        = (float*)d_ws;                     // [N][64]
    float* hB        = hA + (size_t)N * 64;              // [N][64]
    float* means     = hB + (size_t)N * 64;              // [N][192]
    int*   esort     = (int*)(means + (size_t)N * 192);  // [E] (pre-sort)
    int*   rowstartR = esort + E;                        // [4N+4]
    int*   bucket_start = rowstartR + 4 * N + 4;         // [NBKT+1]
    int*   totals    = bucket_start + NBKT + 1;          // [NBKT]
    float* inv_cnt   = (float*)(totals + NBKT);          // [G]
    int*   esort2    = (int*)(inv_cnt + G);              // [E] (sorted, persists)
    int*   pcount    = (int*)means + 4 * 1024 * 1024;    // [NBKT*NCHK] transposed
    int*   pre       = (int*)means + 5 * 1024 * 1024;    // [NCHK*NBKT]

    int embedBlocks = (N * 16 + 255) / 256;              // 3125
    embed_count_kernel<<<embedBlocks + NCHK, 256, 0, stream>>>(
        x, emb, hA, ei, pcount, N, E, NBKT, NCHK, embedBlocks);
    int gBlocks = (G + 255) / 256;                       // graph-bounds tail blocks
    colscan_kernel<<<NBKT + gBlocks, 256, 0, stream>>>(
        pcount, pre, totals, rowstartR, batch, linb, inv_cnt, out,
        NCHK, NBKT, E, N, G);
    scatter_kernel<<<NCHK, 256, 0, stream>>>(ei, et, pre, totals, esort, bucket_start, E, NBKT);
    bucket_sort_kernel<<<NBKT, 256, 0, stream>>>(bucket_start, esort, esort2, rowstartR, N);

    int aggBlocks = (N * 64 + 255) / 256;                // one wave per dst
    int tfBlocks  = (N + 63) / 64;                       // 64 nodes per 256-thr block
    agg_kernel<<<aggBlocks, 256, 0, stream>>>(hA, rowstartR, esort2, means, N);
    transform_kernel<<<tfBlocks, 256, 0, stream>>>(
        hA, means, w1root, w1rel, b1, hB, batch, linw, inv_cnt, out, N, 0);
    agg_kernel<<<aggBlocks, 256, 0, stream>>>(hB, rowstartR, esort2, means, N);
    transform_kernel<<<tfBlocks, 256, 0, stream>>>(
        hB, means, w2root, w2rel, b2, hA, batch, linw, inv_cnt, out, N, 1);
}

// Round 8
// 441.047 us; speedup vs baseline: 1.0425x; 1.0425x over previous
//
#include <hip/hip_runtime.h>

#define CHUNK 2048

// Fused: embed blocks [0,embed_blocks) + per-chunk bucket histogram blocks.
// pcount is stored TRANSPOSED [bucket][chunk] so colscan's read is coalesced.
__global__ __launch_bounds__(256) void embed_count_kernel(
    const int* __restrict__ x, const float* __restrict__ emb, float* __restrict__ h0,
    const int* __restrict__ ei, int* __restrict__ pcount,
    int n_nodes, int n_edges, int n_bkt, int n_chk, int embed_blocks)
{
    __shared__ int cnt[512];
    int t = threadIdx.x;
    if ((int)blockIdx.x < embed_blocks) {
        int tt = blockIdx.x * 256 + t;
        if (tt < n_nodes * 16) {
            int n = tt >> 4, q = tt & 15;
            int xv = x[n];
            float4 v = {0.f, 0.f, 0.f, 0.f};
            if (xv != 0) v = *(const float4*)(emb + (size_t)xv * 64 + q * 4);
            *(float4*)(h0 + (size_t)n * 64 + q * 4) = v;
        }
        return;
    }
    int jb = blockIdx.x - embed_blocks;
    for (int b = t; b < 512; b += 256) cnt[b] = 0;
    __syncthreads();
    int base = jb * CHUNK;
#pragma unroll
    for (int i = 0; i < CHUNK / 256; ++i) {
        int e = base + i * 256 + t;
        if (e < n_edges) atomicAdd(&cnt[ei[n_edges + e] >> 7], 1);
    }
    __syncthreads();
    for (int b = t; b < n_bkt; b += 256) pcount[b * n_chk + jb] = cnt[b];
}

// blocks [0,n_bkt): exclusive scan over chunk counts -> pre, totals.
// blocks [n_bkt, ...): per-graph bounds -> inv_cnt[g]; out[g] init to linb.
__global__ __launch_bounds__(256) void colscan_kernel(
    const int* __restrict__ pcount, int* __restrict__ pre,
    int* __restrict__ totals, int* __restrict__ rowstartR,
    const int* __restrict__ batch, const float* __restrict__ linb,
    float* __restrict__ inv_cnt, float* __restrict__ outg,
    int n_chk, int n_bkt, int n_edges, int n_nodes, int n_graphs)
{
    __shared__ int ps[256];
    int b = blockIdx.x, t = threadIdx.x;
    if (b >= n_bkt) {
        int g = (b - n_bkt) * 256 + t;
        if (g < n_graphs) {
            int lo = 0, hi = n_nodes;
            while (lo < hi) { int mid = (lo + hi) >> 1; if (batch[mid] < g) lo = mid + 1; else hi = mid; }
            int s = lo;
            lo = 0; hi = n_nodes;
            while (lo < hi) { int mid = (lo + hi) >> 1; if (batch[mid] < g + 1) lo = mid + 1; else hi = mid; }
            inv_cnt[g] = 1.f / (float)max(lo - s, 1);
            outg[2 * g + 0] = linb[0];
            outg[2 * g + 1] = linb[1];
        }
        return;
    }
    if (b == 0 && t == 0) rowstartR[4 * n_nodes] = n_edges;
    int v[4], s = 0;
#pragma unroll
    for (int i = 0; i < 4; ++i) {
        int jj = t * 4 + i;
        v[i] = (jj < n_chk) ? pcount[b * n_chk + jj] : 0;
        s += v[i];
    }
    ps[t] = s;
    __syncthreads();
    for (int o = 1; o < 256; o <<= 1) {
        int u = (t >= o) ? ps[t - o] : 0;
        __syncthreads();
        ps[t] += u;
        __syncthreads();
    }
    int run = (t > 0) ? ps[t - 1] : 0;
#pragma unroll
    for (int i = 0; i < 4; ++i) {
        int jj = t * 4 + i;
        if (jj < n_chk) pre[jj * n_bkt + b] = run;
        run += v[i];
    }
    if (t == 255) totals[b] = run;
}

// 611 blocks x 2048 edges; deterministic bases (local scan of totals + pre row),
// LDS fill atomics only. Block 0 publishes bucket_start for the sort.
__global__ __launch_bounds__(256) void scatter_kernel(
    const int* __restrict__ ei, const int* __restrict__ et,
    const int* __restrict__ pre, const int* __restrict__ totals,
    int* __restrict__ esort, int* __restrict__ bucket_start,
    int n_edges, int n_bkt)
{
    __shared__ int bs[512], fill2[512], ps[256];
    int t = threadIdx.x, j = blockIdx.x;
    int a0 = (2 * t < n_bkt) ? totals[2 * t] : 0;
    int a1 = (2 * t + 1 < n_bkt) ? totals[2 * t + 1] : 0;
    ps[t] = a0 + a1;
    __syncthreads();
    for (int o = 1; o < 256; o <<= 1) {
        int u = (t >= o) ? ps[t - o] : 0;
        __syncthreads();
        ps[t] += u;
        __syncthreads();
    }
    int basex = (t > 0) ? ps[t - 1] : 0;
    bs[2 * t] = basex;
    bs[2 * t + 1] = basex + a0;
    fill2[t] = 0; fill2[t + 256] = 0;
    __syncthreads();
    if (j == 0) {
        for (int b = t; b < n_bkt; b += 256) bucket_start[b] = bs[b];
        if (t == 0) bucket_start[n_bkt] = n_edges;
    }
    for (int b = t; b < n_bkt; b += 256) bs[b] += pre[j * n_bkt + b];
    __syncthreads();
    int base = j * CHUNK;
#pragma unroll
    for (int i = 0; i < CHUNK / 256; ++i) {
        int e = base + i * 256 + t;
        if (e < n_edges) {
            int s = ei[e], d = ei[n_edges + e], r = et[e];
            int b = d >> 7;
            int pos = bs[b] + atomicAdd(&fill2[b], 1);
            esort[pos] = s | (r << 16) | ((d & 127) << 18);
        }
    }
}

// one block per bucket: 512-bin counting sort (bin = dstlo*4 + r),
// emits rowstartR[dst*4 + r]. PING-PONG: esort_in -> esort_out.
__global__ __launch_bounds__(256) void bucket_sort_kernel(
    const int* __restrict__ bucket_start, const int* __restrict__ esort_in,
    int* __restrict__ esort_out, int* __restrict__ rowstartR, int n_nodes)
{
    __shared__ int cnt[512], off[512], fill[512], ps[256];
    int t = threadIdx.x, b = blockIdx.x;
    int s = bucket_start[b], e = bucket_start[b + 1];
    cnt[t] = 0; cnt[t + 256] = 0; fill[t] = 0; fill[t + 256] = 0;
    __syncthreads();
    for (int i = s + t; i < e; i += 256)
        atomicAdd(&cnt[(esort_in[i] >> 16) & 0x1FF], 1);
    __syncthreads();
    int a0 = cnt[2 * t], a1 = cnt[2 * t + 1];
    ps[t] = a0 + a1;
    __syncthreads();
    for (int o = 1; o < 256; o <<= 1) {
        int v = (t >= o) ? ps[t - o] : 0;
        __syncthreads();
        ps[t] += v;
        __syncthreads();
    }
    int basex = (t > 0) ? ps[t - 1] : 0;
    off[2 * t] = basex;
    off[2 * t + 1] = basex + a0;
    __syncthreads();
    int d0 = b * 128 + (2 * t >> 2);
    if (d0 < n_nodes) rowstartR[b * 512 + 2 * t] = s + off[2 * t];
    int d1 = b * 128 + ((2 * t + 1) >> 2);
    if (d1 < n_nodes) rowstartR[b * 512 + 2 * t + 1] = s + off[2 * t + 1];
    __syncthreads();
    for (int i = s + t; i < e; i += 256) {
        int p = esort_in[i];
        int bin = (p >> 16) & 0x1FF;
        int pos = s + off[bin] + atomicAdd(&fill[bin], 1);
        esort_out[pos] = p;
    }
}

// one wave per dst. R0's proven version (44.2 us): 4-wide window per quarter,
// plain cached esort loads, 3-way cndmask decode.
__global__ __launch_bounds__(256) void agg_kernel(
    const float* __restrict__ hin, const int* __restrict__ rowstartR,
    const int* __restrict__ esort, float* __restrict__ means, int n_nodes)
{
    int wid = (blockIdx.x * 256 + threadIdx.x) >> 6;
    int lane = threadIdx.x & 63;
    if (wid >= n_nodes) return;
    int q = lane >> 4;
    int c = lane & 15;
    int4 rs = *(const int4*)(rowstartR + wid * 4);
    int s = rs.x, e = rs.w;

    float4 a0 = {0.f,0.f,0.f,0.f}, a1 = {0.f,0.f,0.f,0.f}, a2 = {0.f,0.f,0.f,0.f};

    int i = s + 4 * q;
    for (; i + 4 <= e; i += 16) {
        int p0 = esort[i], p1 = esort[i + 1], p2 = esort[i + 2], p3 = esort[i + 3];
        float4 v0 = *(const float4*)(hin + (size_t)(p0 & 0xFFFF) * 64 + c * 4);
        float4 v1 = *(const float4*)(hin + (size_t)(p1 & 0xFFFF) * 64 + c * 4);
        float4 v2 = *(const float4*)(hin + (size_t)(p2 & 0xFFFF) * 64 + c * 4);
        float4 v3 = *(const float4*)(hin + (size_t)(p3 & 0xFFFF) * 64 + c * 4);
#pragma unroll
        for (int m = 0; m < 4; ++m) {
            int p = m == 0 ? p0 : m == 1 ? p1 : m == 2 ? p2 : p3;
            float4 v = m == 0 ? v0 : m == 1 ? v1 : m == 2 ? v2 : v3;
            int r = (p >> 16) & 3;
            float m0 = (r == 0) ? 1.f : 0.f;
            float m1 = (r == 1) ? 1.f : 0.f;
            float m2 = (r == 2) ? 1.f : 0.f;
            a0.x = fmaf(m0, v.x, a0.x); a0.y = fmaf(m0, v.y, a0.y);
            a0.z = fmaf(m0, v.z, a0.z); a0.w = fmaf(m0, v.w, a0.w);
            a1.x = fmaf(m1, v.x, a1.x); a1.y = fmaf(m1, v.y, a1.y);
            a1.z = fmaf(m1, v.z, a1.z); a1.w = fmaf(m1, v.w, a1.w);
            a2.x = fmaf(m2, v.x, a2.x); a2.y = fmaf(m2, v.y, a2.y);
            a2.z = fmaf(m2, v.z, a2.z); a2.w = fmaf(m2, v.w, a2.w);
        }
    }
#pragma unroll
    for (int m = 0; m < 3; ++m) {
        int ii = i + m;
        if (ii < e) {
            int p = esort[ii];
            float4 v = *(const float4*)(hin + (size_t)(p & 0xFFFF) * 64 + c * 4);
            int r = (p >> 16) & 3;
            float m0 = (r == 0) ? 1.f : 0.f;
            float m1 = (r == 1) ? 1.f : 0.f;
            float m2 = (r == 2) ? 1.f : 0.f;
            a0.x = fmaf(m0, v.x, a0.x); a0.y = fmaf(m0, v.y, a0.y);
            a0.z = fmaf(m0, v.z, a0.z); a0.w = fmaf(m0, v.w, a0.w);
            a1.x = fmaf(m1, v.x, a1.x); a1.y = fmaf(m1, v.y, a1.y);
            a1.z = fmaf(m1, v.z, a1.z); a1.w = fmaf(m1, v.w, a1.w);
            a2.x = fmaf(m2, v.x, a2.x); a2.y = fmaf(m2, v.y, a2.y);
            a2.z = fmaf(m2, v.z, a2.z); a2.w = fmaf(m2, v.w, a2.w);
        }
    }
#pragma unroll
    for (int off = 16; off < 64; off <<= 1) {
        a0.x += __shfl_xor(a0.x, off); a0.y += __shfl_xor(a0.y, off);
        a0.z += __shfl_xor(a0.z, off); a0.w += __shfl_xor(a0.w, off);
        a1.x += __shfl_xor(a1.x, off); a1.y += __shfl_xor(a1.y, off);
        a1.z += __shfl_xor(a1.z, off); a1.w += __shfl_xor(a1.w, off);
        a2.x += __shfl_xor(a2.x, off); a2.y += __shfl_xor(a2.y, off);
        a2.z += __shfl_xor(a2.z, off); a2.w += __shfl_xor(a2.w, off);
    }
    if (q < 3) {
        int cnt = (q == 0) ? (rs.y - rs.x) : (q == 1) ? (rs.z - rs.y) : (rs.w - rs.z);
        float4 a = (q == 0) ? a0 : (q == 1) ? a1 : a2;
        float inv = 1.f / (float)max(cnt, 1);
        float4 m = {a.x * inv, a.y * inv, a.z * inv, a.w * inv};
        *(float4*)(means + (size_t)wid * 192 + q * 64 + c * 4) = m;
    }
}

// ---------------------------------------------------------------------------
// transform, lane-per-node layout, v hoisted in 4-float4 CHUNKS.
// R7 post-mortem: vr[16] (64 VGPR) + acc + stg overflowed the allocator ->
// spill to scratch (VGPR_Count 60, WRITE_SIZE 37->72MB, dur 131us). The
// lgkmcnt-mixing theory (R6: ds_read and s_load share lgkmcnt, SMEM is
// out-of-order -> each ds_read wait drains the s_load pipeline) was never
// actually tested. This version tests it cleanly: per phase, 4 chunks of
// {4 ds_read_b128 -> ONE lgkmcnt drain -> 256 FMAs with only s_loads
// outstanding}. 4 drains/phase (vs 16 in R6), each followed by ~512cy of
// VALU work that covers the s_load pipeline restart. vr[4]=16 VGPR ->
// total ~75-85, no spill at the 128-VGPR budget of launch_bounds(256,4).
// Decision rule: if still ~45us with no spill artifacts, theory falsified,
// transform plateaus; move to agg/preproc.
// ---------------------------------------------------------------------------
__global__ __launch_bounds__(256, 4) void transform_kernel(
    const float* __restrict__ hin, const float* __restrict__ means,
    const float* __restrict__ wroot, const float* __restrict__ wrel,
    const float* __restrict__ bias, float* __restrict__ hout,
    const int* __restrict__ batch, const float* __restrict__ linw,
    const float* __restrict__ inv_cnt, float* __restrict__ outg,
    int n_nodes, int do_pool)
{
    __shared__ float smem[2][64 * 68];   // 2 x 17 KB v double-buffer (+reused epilogue)
    int t = threadIdx.x;
    int lane = t & 63;
    int wv = __builtin_amdgcn_readfirstlane(t >> 6);
    int j0 = wv * 16;
    int n0g = blockIdx.x * 64;

    int sn_ = t >> 4;            // staging: node sub-index within a round
    int sk  = (t & 15) * 4;      // staging: k offset (16 threads cover a row)

    float4 stg[4];
    // prologue: stage phase 0 (contiguous h slice) into smem[0]
#pragma unroll
    for (int r = 0; r < 4; ++r) {
        int node = r * 16 + sn_;
        int gn = min(n0g + node, n_nodes - 1);
        stg[r] = *(const float4*)(hin + (size_t)gn * 64 + sk);
    }
#pragma unroll
    for (int r = 0; r < 4; ++r) {
        int node = r * 16 + sn_;
        *(float4*)&smem[0][node * 68 + sk] = stg[r];
    }

    float acc[16];
#pragma unroll
    for (int i = 0; i < 16; ++i) acc[i] = bias[j0 + i];   // uniform -> s_load
    __syncthreads();

    for (int p = 0; p < 4; ++p) {
        if (p < 3) {   // issue next phase's global loads early (hide under FMAs)
#pragma unroll
            for (int r = 0; r < 4; ++r) {
                int node = r * 16 + sn_;
                int gn = min(n0g + node, n_nodes - 1);
                stg[r] = *(const float4*)(means + (size_t)gn * 192 + p * 64 + sk);
            }
        }
        const float* lv = &smem[p & 1][lane * 68];
        const float* wb = ((p == 0) ? wroot : (wrel + (size_t)(p - 1) * 4096)) + j0;
#pragma unroll
        for (int c4 = 0; c4 < 4; ++c4) {
            // ---- 4-float4 v chunk LDS -> VGPRs, one lgkmcnt drain ----
            float4 vr[4];
#pragma unroll
            for (int u = 0; u < 4; ++u)
                vr[u] = *(const float4*)(lv + (c4 * 4 + u) * 4);
            // ---- pure s_load + FMA stream (no DS waits inside) ----
#pragma unroll
            for (int u = 0; u < 4; ++u) {
#pragma unroll
                for (int kk = 0; kk < 4; ++kk) {
                    float vk = kk == 0 ? vr[u].x : kk == 1 ? vr[u].y
                             : kk == 2 ? vr[u].z : vr[u].w;
                    const float* wr = wb + ((c4 * 4 + u) * 4 + kk) * 64;  // uniform
#pragma unroll
                    for (int i = 0; i < 16; ++i)
                        acc[i] = fmaf(vk, wr[i], acc[i]);
                }
            }
        }
        if (p < 3) {
            __syncthreads();     // all waves done reading buf[(p+1)&1] (phase p-1)
#pragma unroll
            for (int r = 0; r < 4; ++r) {
                int node = r * 16 + sn_;
                *(float4*)&smem[(p + 1) & 1][node * 68 + sk] = stg[r];
            }
            __syncthreads();     // staged data visible before phase p+1 reads
        }
    }

    if (!do_pool) {
        __syncthreads();         // everyone past phase-2 reads -> smem[0] free
        float* osh = smem[0];    // [64][68] transpose turnaround
#pragma unroll
        for (int i4 = 0; i4 < 4; ++i4) {
            float4 r;
            r.x = fmaxf(acc[i4 * 4 + 0], 0.f);
            r.y = fmaxf(acc[i4 * 4 + 1], 0.f);
            r.z = fmaxf(acc[i4 * 4 + 2], 0.f);
            r.w = fmaxf(acc[i4 * 4 + 3], 0.f);
            *(float4*)&osh[lane * 68 + j0 + i4 * 4] = r;
        }
        __syncthreads();
#pragma unroll
        for (int r = 0; r < 4; ++r) {
            int node = r * 16 + sn_;
            int gn = n0g + node;
            if (gn < n_nodes)
                *(float4*)(hout + (size_t)gn * 64 + sk) =
                    *(const float4*)&osh[node * 68 + sk];
        }
    } else {
        float d0 = 0.f, d1 = 0.f;
#pragma unroll
        for (int i = 0; i < 16; ++i) {
            float rr = fmaxf(acc[i], 0.f);
            d0 = fmaf(rr, linw[(j0 + i) * 2 + 0], d0);   // uniform -> s_load
            d1 = fmaf(rr, linw[(j0 + i) * 2 + 1], d1);
        }
        __syncthreads();                 // compute buffers free
        float* wsum = smem[0];           // [4][64][2]
        float* gacc = smem[0] + 512;     // [64][2]
        wsum[(wv * 64 + lane) * 2 + 0] = d0;
        wsum[(wv * 64 + lane) * 2 + 1] = d1;
        if (t < 128) gacc[t] = 0.f;
        __syncthreads();
        int gmin = batch[min(n0g, n_nodes - 1)];
        if (t < 64) {
            int gn = n0g + t;
            if (gn < n_nodes) {
                float s0 = wsum[t * 2]     + wsum[128 + t * 2] +
                           wsum[256 + t * 2] + wsum[384 + t * 2];
                float s1 = wsum[t * 2 + 1]     + wsum[128 + t * 2 + 1] +
                           wsum[256 + t * 2 + 1] + wsum[384 + t * 2 + 1];
                int gg = batch[gn];
                float ic = inv_cnt[gg];
                int idx = gg - gmin;
                if (idx < 64) {
                    atomicAdd(&gacc[idx * 2 + 0], s0 * ic);
                    atomicAdd(&gacc[idx * 2 + 1], s1 * ic);
                } else {   // empty-graph gap fallback (practically never)
                    atomicAdd(&outg[2 * gg + 0], s0 * ic);
                    atomicAdd(&outg[2 * gg + 1], s1 * ic);
                }
            }
        }
        __syncthreads();
        if (t < 64) {
            float v0 = gacc[t * 2], v1 = gacc[t * 2 + 1];
            if (v0 != 0.f || v1 != 0.f) {
                atomicAdd(&outg[2 * (gmin + t) + 0], v0);
                atomicAdd(&outg[2 * (gmin + t) + 1], v1);
            }
        }
    }
}

extern "C" void kernel_launch(void* const* d_in, const int* in_sizes, int n_in,
                              void* d_out, int out_size, void* d_ws, size_t ws_size,
                              hipStream_t stream)
{
    const int*   x      = (const int*)d_in[0];
    const int*   ei     = (const int*)d_in[1];
    const int*   et     = (const int*)d_in[2];
    const int*   batch  = (const int*)d_in[3];
    const float* emb    = (const float*)d_in[4];
    const float* w1rel  = (const float*)d_in[5];
    const float* w1root = (const float*)d_in[6];
    const float* b1     = (const float*)d_in[7];
    const float* w2rel  = (const float*)d_in[8];
    const float* w2root = (const float*)d_in[9];
    const float* b2     = (const float*)d_in[10];
    const float* linw   = (const float*)d_in[11];
    const float* linb   = (const float*)d_in[12];
    float* out = (float*)d_out;

    const int N = in_sizes[0];            // 50000
    const int E = in_sizes[2];            // 1250000
    const int G = out_size / 2;           // 512
    const int NBKT = (N + 127) >> 7;      // 391
    const int NCHK = (E + CHUNK - 1) / CHUNK;  // 611

    float* hA        = (float*)d_ws;                     // [N][64]
    float* hB        = hA + (size_t)N * 64;              // [N][64]
    float* means     = hB + (size_t)N * 64;              // [N][192]
    int*   esort     = (int*)(means + (size_t)N * 192);  // [E] (pre-sort)
    int*   rowstartR = esort + E;                        // [4N+4]
    int*   bucket_start = rowstartR + 4 * N + 4;         // [NBKT+1]
    int*   totals    = bucket_start + NBKT + 1;          // [NBKT]
    float* inv_cnt   = (float*)(totals + NBKT);          // [G]
    int*   esort2    = (int*)(inv_cnt + G);              // [E] (sorted, persists)
    int*   pcount    = (int*)means + 4 * 1024 * 1024;    // [NBKT*NCHK] transposed
    int*   pre       = (int*)means + 5 * 1024 * 1024;    // [NCHK*NBKT]

    int embedBlocks = (N * 16 + 255) / 256;              // 3125
    embed_count_kernel<<<embedBlocks + NCHK, 256, 0, stream>>>(
        x, emb, hA, ei, pcount, N, E, NBKT, NCHK, embedBlocks);
    int gBlocks = (G + 255) / 256;                       // graph-bounds tail blocks
    colscan_kernel<<<NBKT + gBlocks, 256, 0, stream>>>(
        pcount, pre, totals, rowstartR, batch, linb, inv_cnt, out,
        NCHK, NBKT, E, N, G);
    scatter_kernel<<<NCHK, 256, 0, stream>>>(ei, et, pre, totals, esort, bucket_start, E, NBKT);
    bucket_sort_kernel<<<NBKT, 256, 0, stream>>>(bucket_start, esort, esort2, rowstartR, N);

    int aggBlocks = (N * 64 + 255) / 256;                // one wave per dst
    int tfBlocks  = (N + 63) / 64;                       // 64 nodes per 256-thr block
    agg_kernel<<<aggBlocks, 256, 0, stream>>>(hA, rowstartR, esort2, means, N);
    transform_kernel<<<tfBlocks, 256, 0, stream>>>(
        hA, means, w1root, w1rel, b1, hB, batch, linw, inv_cnt, out, N, 0);
    agg_kernel<<<aggBlocks, 256, 0, stream>>>(hB, rowstartR, esort2, means, N);
    transform_kernel<<<tfBlocks, 256, 0, stream>>>(
        hB, means, w2root, w2rel, b2, hA, batch, linw, inv_cnt, out, N, 1);
}

// Round 9
// 298.690 us; speedup vs baseline: 1.5393x; 1.4766x over previous
//
#include <hip/hip_runtime.h>

#define CHUNK 2048

// Fused: embed blocks [0,embed_blocks) + per-chunk bucket histogram blocks
// [embed_blocks, embed_blocks+n_chk) + graph-bounds/out-init tail blocks
// (moved here from colscan: they depend only on batch/linb, so running them
// in this first kernel shortens colscan's critical path).
// pcount is stored TRANSPOSED [bucket][chunk] so colscan's read is coalesced.
__global__ __launch_bounds__(256) void embed_count_kernel(
    const int* __restrict__ x, const float* __restrict__ emb, float* __restrict__ h0,
    const int* __restrict__ ei, int* __restrict__ pcount,
    const int* __restrict__ batch, const float* __restrict__ linb,
    float* __restrict__ inv_cnt, float* __restrict__ outg,
    int n_nodes, int n_edges, int n_bkt, int n_chk, int n_graphs,
    int embed_blocks)
{
    __shared__ int cnt[512];
    int t = threadIdx.x;
    if ((int)blockIdx.x < embed_blocks) {
        int tt = blockIdx.x * 256 + t;
        if (tt < n_nodes * 16) {
            int n = tt >> 4, q = tt & 15;
            int xv = x[n];
            float4 v = {0.f, 0.f, 0.f, 0.f};
            if (xv != 0) v = *(const float4*)(emb + (size_t)xv * 64 + q * 4);
            *(float4*)(h0 + (size_t)n * 64 + q * 4) = v;
        }
        return;
    }
    if ((int)blockIdx.x >= embed_blocks + n_chk) {   // graph-bounds tail
        int g = (blockIdx.x - embed_blocks - n_chk) * 256 + t;
        if (g < n_graphs) {
            int lo = 0, hi = n_nodes;
            while (lo < hi) { int mid = (lo + hi) >> 1; if (batch[mid] < g) lo = mid + 1; else hi = mid; }
            int s = lo;
            lo = 0; hi = n_nodes;
            while (lo < hi) { int mid = (lo + hi) >> 1; if (batch[mid] < g + 1) lo = mid + 1; else hi = mid; }
            inv_cnt[g] = 1.f / (float)max(lo - s, 1);
            outg[2 * g + 0] = linb[0];
            outg[2 * g + 1] = linb[1];
        }
        return;
    }
    int jb = blockIdx.x - embed_blocks;
    for (int b = t; b < 512; b += 256) cnt[b] = 0;
    __syncthreads();
    int base = jb * CHUNK;
#pragma unroll
    for (int i = 0; i < CHUNK / 256; ++i) {
        int e = base + i * 256 + t;
        if (e < n_edges) atomicAdd(&cnt[ei[n_edges + e] >> 7], 1);
    }
    __syncthreads();
    for (int b = t; b < n_bkt; b += 256) pcount[b * n_chk + jb] = cnt[b];
}

// blocks [0,n_bkt): exclusive scan over chunk counts -> pre, totals.
// (graph-bounds work moved to embed_count_kernel.)
__global__ __launch_bounds__(256) void colscan_kernel(
    const int* __restrict__ pcount, int* __restrict__ pre,
    int* __restrict__ totals, int* __restrict__ rowstartR,
    int n_chk, int n_bkt, int n_edges, int n_nodes)
{
    __shared__ int ps[256];
    int b = blockIdx.x, t = threadIdx.x;
    if (b == 0 && t == 0) rowstartR[4 * n_nodes] = n_edges;
    int v[4], s = 0;
#pragma unroll
    for (int i = 0; i < 4; ++i) {
        int jj = t * 4 + i;
        v[i] = (jj < n_chk) ? pcount[b * n_chk + jj] : 0;
        s += v[i];
    }
    ps[t] = s;
    __syncthreads();
    for (int o = 1; o < 256; o <<= 1) {
        int u = (t >= o) ? ps[t - o] : 0;
        __syncthreads();
        ps[t] += u;
        __syncthreads();
    }
    int run = (t > 0) ? ps[t - 1] : 0;
#pragma unroll
    for (int i = 0; i < 4; ++i) {
        int jj = t * 4 + i;
        if (jj < n_chk) pre[jj * n_bkt + b] = run;
        run += v[i];
    }
    if (t == 255) totals[b] = run;
}

// 611 blocks x 2048 edges; deterministic bases (local scan of totals + pre row),
// LDS fill atomics only. Block 0 publishes bucket_start for the sort.
__global__ __launch_bounds__(256) void scatter_kernel(
    const int* __restrict__ ei, const int* __restrict__ et,
    const int* __restrict__ pre, const int* __restrict__ totals,
    int* __restrict__ esort, int* __restrict__ bucket_start,
    int n_edges, int n_bkt)
{
    __shared__ int bs[512], fill2[512], ps[256];
    int t = threadIdx.x, j = blockIdx.x;
    int a0 = (2 * t < n_bkt) ? totals[2 * t] : 0;
    int a1 = (2 * t + 1 < n_bkt) ? totals[2 * t + 1] : 0;
    ps[t] = a0 + a1;
    __syncthreads();
    for (int o = 1; o < 256; o <<= 1) {
        int u = (t >= o) ? ps[t - o] : 0;
        __syncthreads();
        ps[t] += u;
        __syncthreads();
    }
    int basex = (t > 0) ? ps[t - 1] : 0;
    bs[2 * t] = basex;
    bs[2 * t + 1] = basex + a0;
    fill2[t] = 0; fill2[t + 256] = 0;
    __syncthreads();
    if (j == 0) {
        for (int b = t; b < n_bkt; b += 256) bucket_start[b] = bs[b];
        if (t == 0) bucket_start[n_bkt] = n_edges;
    }
    for (int b = t; b < n_bkt; b += 256) bs[b] += pre[j * n_bkt + b];
    __syncthreads();
    int base = j * CHUNK;
#pragma unroll
    for (int i = 0; i < CHUNK / 256; ++i) {
        int e = base + i * 256 + t;
        if (e < n_edges) {
            int s = ei[e], d = ei[n_edges + e], r = et[e];
            int b = d >> 7;
            int pos = bs[b] + atomicAdd(&fill2[b], 1);
            esort[pos] = s | (r << 16) | ((d & 127) << 18);
        }
    }
}

// one block per bucket: 512-bin counting sort (bin = dstlo*4 + r),
// emits rowstartR[dst*4 + r]. PING-PONG: esort_in -> esort_out.
__global__ __launch_bounds__(256) void bucket_sort_kernel(
    const int* __restrict__ bucket_start, const int* __restrict__ esort_in,
    int* __restrict__ esort_out, int* __restrict__ rowstartR, int n_nodes)
{
    __shared__ int cnt[512], off[512], fill[512], ps[256];
    int t = threadIdx.x, b = blockIdx.x;
    int s = bucket_start[b], e = bucket_start[b + 1];
    cnt[t] = 0; cnt[t + 256] = 0; fill[t] = 0; fill[t + 256] = 0;
    __syncthreads();
    for (int i = s + t; i < e; i += 256)
        atomicAdd(&cnt[(esort_in[i] >> 16) & 0x1FF], 1);
    __syncthreads();
    int a0 = cnt[2 * t], a1 = cnt[2 * t + 1];
    ps[t] = a0 + a1;
    __syncthreads();
    for (int o = 1; o < 256; o <<= 1) {
        int v = (t >= o) ? ps[t - o] : 0;
        __syncthreads();
        ps[t] += v;
        __syncthreads();
    }
    int basex = (t > 0) ? ps[t - 1] : 0;
    off[2 * t] = basex;
    off[2 * t + 1] = basex + a0;
    __syncthreads();
    int d0 = b * 128 + (2 * t >> 2);
    if (d0 < n_nodes) rowstartR[b * 512 + 2 * t] = s + off[2 * t];
    int d1 = b * 128 + ((2 * t + 1) >> 2);
    if (d1 < n_nodes) rowstartR[b * 512 + 2 * t + 1] = s + off[2 * t + 1];
    __syncthreads();
    for (int i = s + t; i < e; i += 256) {
        int p = esort_in[i];
        int bin = (p >> 16) & 0x1FF;
        int pos = s + off[bin] + atomicAdd(&fill[bin], 1);
        esort_out[pos] = p;
    }
}

// one wave per dst. R0's proven version (44.2 us): 4-wide window per quarter,
// plain cached esort loads, 3-way cndmask decode.
__global__ __launch_bounds__(256) void agg_kernel(
    const float* __restrict__ hin, const int* __restrict__ rowstartR,
    const int* __restrict__ esort, float* __restrict__ means, int n_nodes)
{
    int wid = (blockIdx.x * 256 + threadIdx.x) >> 6;
    int lane = threadIdx.x & 63;
    if (wid >= n_nodes) return;
    int q = lane >> 4;
    int c = lane & 15;
    int4 rs = *(const int4*)(rowstartR + wid * 4);
    int s = rs.x, e = rs.w;

    float4 a0 = {0.f,0.f,0.f,0.f}, a1 = {0.f,0.f,0.f,0.f}, a2 = {0.f,0.f,0.f,0.f};

    int i = s + 4 * q;
    for (; i + 4 <= e; i += 16) {
        int p0 = esort[i], p1 = esort[i + 1], p2 = esort[i + 2], p3 = esort[i + 3];
        float4 v0 = *(const float4*)(hin + (size_t)(p0 & 0xFFFF) * 64 + c * 4);
        float4 v1 = *(const float4*)(hin + (size_t)(p1 & 0xFFFF) * 64 + c * 4);
        float4 v2 = *(const float4*)(hin + (size_t)(p2 & 0xFFFF) * 64 + c * 4);
        float4 v3 = *(const float4*)(hin + (size_t)(p3 & 0xFFFF) * 64 + c * 4);
#pragma unroll
        for (int m = 0; m < 4; ++m) {
            int p = m == 0 ? p0 : m == 1 ? p1 : m == 2 ? p2 : p3;
            float4 v = m == 0 ? v0 : m == 1 ? v1 : m == 2 ? v2 : v3;
            int r = (p >> 16) & 3;
            float m0 = (r == 0) ? 1.f : 0.f;
            float m1 = (r == 1) ? 1.f : 0.f;
            float m2 = (r == 2) ? 1.f : 0.f;
            a0.x = fmaf(m0, v.x, a0.x); a0.y = fmaf(m0, v.y, a0.y);
            a0.z = fmaf(m0, v.z, a0.z); a0.w = fmaf(m0, v.w, a0.w);
            a1.x = fmaf(m1, v.x, a1.x); a1.y = fmaf(m1, v.y, a1.y);
            a1.z = fmaf(m1, v.z, a1.z); a1.w = fmaf(m1, v.w, a1.w);
            a2.x = fmaf(m2, v.x, a2.x); a2.y = fmaf(m2, v.y, a2.y);
            a2.z = fmaf(m2, v.z, a2.z); a2.w = fmaf(m2, v.w, a2.w);
        }
    }
#pragma unroll
    for (int m = 0; m < 3; ++m) {
        int ii = i + m;
        if (ii < e) {
            int p = esort[ii];
            float4 v = *(const float4*)(hin + (size_t)(p & 0xFFFF) * 64 + c * 4);
            int r = (p >> 16) & 3;
            float m0 = (r == 0) ? 1.f : 0.f;
            float m1 = (r == 1) ? 1.f : 0.f;
            float m2 = (r == 2) ? 1.f : 0.f;
            a0.x = fmaf(m0, v.x, a0.x); a0.y = fmaf(m0, v.y, a0.y);
            a0.z = fmaf(m0, v.z, a0.z); a0.w = fmaf(m0, v.w, a0.w);
            a1.x = fmaf(m1, v.x, a1.x); a1.y = fmaf(m1, v.y, a1.y);
            a1.z = fmaf(m1, v.z, a1.z); a1.w = fmaf(m1, v.w, a1.w);
            a2.x = fmaf(m2, v.x, a2.x); a2.y = fmaf(m2, v.y, a2.y);
            a2.z = fmaf(m2, v.z, a2.z); a2.w = fmaf(m2, v.w, a2.w);
        }
    }
#pragma unroll
    for (int off = 16; off < 64; off <<= 1) {
        a0.x += __shfl_xor(a0.x, off); a0.y += __shfl_xor(a0.y, off);
        a0.z += __shfl_xor(a0.z, off); a0.w += __shfl_xor(a0.w, off);
        a1.x += __shfl_xor(a1.x, off); a1.y += __shfl_xor(a1.y, off);
        a1.z += __shfl_xor(a1.z, off); a1.w += __shfl_xor(a1.w, off);
        a2.x += __shfl_xor(a2.x, off); a2.y += __shfl_xor(a2.y, off);
        a2.z += __shfl_xor(a2.z, off); a2.w += __shfl_xor(a2.w, off);
    }
    if (q < 3) {
        int cnt = (q == 0) ? (rs.y - rs.x) : (q == 1) ? (rs.z - rs.y) : (rs.w - rs.z);
        float4 a = (q == 0) ? a0 : (q == 1) ? a1 : a2;
        float inv = 1.f / (float)max(cnt, 1);
        float4 m = {a.x * inv, a.y * inv, a.z * inv, a.w * inv};
        *(float4*)(means + (size_t)wid * 192 + q * 64 + c * 4) = m;
    }
}

// ---------------------------------------------------------------------------
// transform, lane-per-node layout -- EXACT R6 version (measured 45us, VGPR 52,
// no scratch). R7/R8 attempts to hoist the v-row into VGPRs both triggered
// compiler scratch allocation (VGPR_Count pinned at 60, WRITE_SIZE +25-35MB,
// dur 110-131us) despite fitting the 128-VGPR budget on paper -- that line is
// abandoned. Transform has measured ~45-47us across five structurally
// different implementations (occupancy 12-24 waves/CU, LDS-pipe floors
// 15-31us, scalar-W vs LDS-W): latency-bound plateau at this structure.
//  - block = 256 thr = 64 nodes; wave w owns cols [16w,16w+16); lane = node.
//  - v (h/means) staged per-phase to LDS, reg-staged coalesced, dbuffered.
//  - W wave-uniform (j0 readfirstlane'd) -> s_load; FMA = VGPR*SGPR+VGPR.
//  - outputs via LDS transpose turnaround; do_pool: per-lane head partials
//    -> 4-wave LDS reduce -> per-graph gacc -> ~2 global atomics/block.
// ---------------------------------------------------------------------------
__global__ __launch_bounds__(256, 4) void transform_kernel(
    const float* __restrict__ hin, const float* __restrict__ means,
    const float* __restrict__ wroot, const float* __restrict__ wrel,
    const float* __restrict__ bias, float* __restrict__ hout,
    const int* __restrict__ batch, const float* __restrict__ linw,
    const float* __restrict__ inv_cnt, float* __restrict__ outg,
    int n_nodes, int do_pool)
{
    __shared__ float smem[2][64 * 68];   // 2 x 17 KB v double-buffer (+reused epilogue)
    int t = threadIdx.x;
    int lane = t & 63;
    int wv = __builtin_amdgcn_readfirstlane(t >> 6);
    int j0 = wv * 16;
    int n0g = blockIdx.x * 64;

    int sn_ = t >> 4;            // staging: node sub-index within a round
    int sk  = (t & 15) * 4;      // staging: k offset (16 threads cover a row)

    float4 stg[4];
    // prologue: stage phase 0 (contiguous h slice) into smem[0]
#pragma unroll
    for (int r = 0; r < 4; ++r) {
        int node = r * 16 + sn_;
        int gn = min(n0g + node, n_nodes - 1);
        stg[r] = *(const float4*)(hin + (size_t)gn * 64 + sk);
    }
#pragma unroll
    for (int r = 0; r < 4; ++r) {
        int node = r * 16 + sn_;
        *(float4*)&smem[0][node * 68 + sk] = stg[r];
    }

    float acc[16];
#pragma unroll
    for (int i = 0; i < 16; ++i) acc[i] = bias[j0 + i];   // uniform -> s_load
    __syncthreads();

    for (int p = 0; p < 4; ++p) {
        if (p < 3) {   // issue next phase's global loads early (hide under FMAs)
#pragma unroll
            for (int r = 0; r < 4; ++r) {
                int node = r * 16 + sn_;
                int gn = min(n0g + node, n_nodes - 1);
                stg[r] = *(const float4*)(means + (size_t)gn * 192 + p * 64 + sk);
            }
        }
        const float* wb = ((p == 0) ? wroot : (wrel + (size_t)(p - 1) * 4096)) + j0;
        const float* lv = &smem[p & 1][lane * 68];
#pragma unroll 4
        for (int k4 = 0; k4 < 16; ++k4) {
            float4 v = *(const float4*)(lv + k4 * 4);
#pragma unroll
            for (int kk = 0; kk < 4; ++kk) {
                float vk = kk == 0 ? v.x : kk == 1 ? v.y : kk == 2 ? v.z : v.w;
                const float* wr = wb + (k4 * 4 + kk) * 64;   // uniform row -> s_load
#pragma unroll
                for (int i = 0; i < 16; ++i)
                    acc[i] = fmaf(vk, wr[i], acc[i]);
            }
        }
        if (p < 3) {
            __syncthreads();     // all waves done reading buf[(p+1)&1] (phase p-1)
#pragma unroll
            for (int r = 0; r < 4; ++r) {
                int node = r * 16 + sn_;
                *(float4*)&smem[(p + 1) & 1][node * 68 + sk] = stg[r];
            }
            __syncthreads();     // staged data visible before phase p+1 reads
        }
    }

    if (!do_pool) {
        __syncthreads();         // everyone past phase-2 reads -> smem[0] free
        float* osh = smem[0];    // [64][68] transpose turnaround
#pragma unroll
        for (int i4 = 0; i4 < 4; ++i4) {
            float4 r;
            r.x = fmaxf(acc[i4 * 4 + 0], 0.f);
            r.y = fmaxf(acc[i4 * 4 + 1], 0.f);
            r.z = fmaxf(acc[i4 * 4 + 2], 0.f);
            r.w = fmaxf(acc[i4 * 4 + 3], 0.f);
            *(float4*)&osh[lane * 68 + j0 + i4 * 4] = r;
        }
        __syncthreads();
#pragma unroll
        for (int r = 0; r < 4; ++r) {
            int node = r * 16 + sn_;
            int gn = n0g + node;
            if (gn < n_nodes)
                *(float4*)(hout + (size_t)gn * 64 + sk) =
                    *(const float4*)&osh[node * 68 + sk];
        }
    } else {
        float d0 = 0.f, d1 = 0.f;
#pragma unroll
        for (int i = 0; i < 16; ++i) {
            float rr = fmaxf(acc[i], 0.f);
            d0 = fmaf(rr, linw[(j0 + i) * 2 + 0], d0);   // uniform -> s_load
            d1 = fmaf(rr, linw[(j0 + i) * 2 + 1], d1);
        }
        __syncthreads();                 // compute buffers free
        float* wsum = smem[0];           // [4][64][2]
        float* gacc = smem[0] + 512;     // [64][2]
        wsum[(wv * 64 + lane) * 2 + 0] = d0;
        wsum[(wv * 64 + lane) * 2 + 1] = d1;
        if (t < 128) gacc[t] = 0.f;
        __syncthreads();
        int gmin = batch[min(n0g, n_nodes - 1)];
        if (t < 64) {
            int gn = n0g + t;
            if (gn < n_nodes) {
                float s0 = wsum[t * 2]     + wsum[128 + t * 2] +
                           wsum[256 + t * 2] + wsum[384 + t * 2];
                float s1 = wsum[t * 2 + 1]     + wsum[128 + t * 2 + 1] +
                           wsum[256 + t * 2 + 1] + wsum[384 + t * 2 + 1];
                int gg = batch[gn];
                float ic = inv_cnt[gg];
                int idx = gg - gmin;
                if (idx < 64) {
                    atomicAdd(&gacc[idx * 2 + 0], s0 * ic);
                    atomicAdd(&gacc[idx * 2 + 1], s1 * ic);
                } else {   // empty-graph gap fallback (practically never)
                    atomicAdd(&outg[2 * gg + 0], s0 * ic);
                    atomicAdd(&outg[2 * gg + 1], s1 * ic);
                }
            }
        }
        __syncthreads();
        if (t < 64) {
            float v0 = gacc[t * 2], v1 = gacc[t * 2 + 1];
            if (v0 != 0.f || v1 != 0.f) {
                atomicAdd(&outg[2 * (gmin + t) + 0], v0);
                atomicAdd(&outg[2 * (gmin + t) + 1], v1);
            }
        }
    }
}

extern "C" void kernel_launch(void* const* d_in, const int* in_sizes, int n_in,
                              void* d_out, int out_size, void* d_ws, size_t ws_size,
                              hipStream_t stream)
{
    const int*   x      = (const int*)d_in[0];
    const int*   ei     = (const int*)d_in[1];
    const int*   et     = (const int*)d_in[2];
    const int*   batch  = (const int*)d_in[3];
    const float* emb    = (const float*)d_in[4];
    const float* w1rel  = (const float*)d_in[5];
    const float* w1root = (const float*)d_in[6];
    const float* b1     = (const float*)d_in[7];
    const float* w2rel  = (const float*)d_in[8];
    const float* w2root = (const float*)d_in[9];
    const float* b2     = (const float*)d_in[10];
    const float* linw   = (const float*)d_in[11];
    const float* linb   = (const float*)d_in[12];
    float* out = (float*)d_out;

    const int N = in_sizes[0];            // 50000
    const int E = in_sizes[2];            // 1250000
    const int G = out_size / 2;           // 512
    const int NBKT = (N + 127) >> 7;      // 391
    const int NCHK = (E + CHUNK - 1) / CHUNK;  // 611

    float* hA        = (float*)d_ws;                     // [N][64]
    float* hB        = hA + (size_t)N * 64;              // [N][64]
    float* means     = hB + (size_t)N * 64;              // [N][192]
    int*   esort     = (int*)(means + (size_t)N * 192);  // [E] (pre-sort)
    int*   rowstartR = esort + E;                        // [4N+4]
    int*   bucket_start = rowstartR + 4 * N + 4;         // [NBKT+1]
    int*   totals    = bucket_start + NBKT + 1;          // [NBKT]
    float* inv_cnt   = (float*)(totals + NBKT);          // [G]
    int*   esort2    = (int*)(inv_cnt + G);              // [E] (sorted, persists)
    int*   pcount    = (int*)means + 4 * 1024 * 1024;    // [NBKT*NCHK] transposed
    int*   pre       = (int*)means + 5 * 1024 * 1024;    // [NCHK*NBKT]

    int embedBlocks = (N * 16 + 255) / 256;              // 3125
    int gBlocks = (G + 255) / 256;                       // graph-bounds tail blocks
    embed_count_kernel<<<embedBlocks + NCHK + gBlocks, 256, 0, stream>>>(
        x, emb, hA, ei, pcount, batch, linb, inv_cnt, out,
        N, E, NBKT, NCHK, G, embedBlocks);
    colscan_kernel<<<NBKT, 256, 0, stream>>>(
        pcount, pre, totals, rowstartR, NCHK, NBKT, E, N);
    scatter_kernel<<<NCHK, 256, 0, stream>>>(ei, et, pre, totals, esort, bucket_start, E, NBKT);
    bucket_sort_kernel<<<NBKT, 256, 0, stream>>>(bucket_start, esort, esort2, rowstartR, N);

    int aggBlocks = (N * 64 + 255) / 256;                // one wave per dst
    int tfBlocks  = (N + 63) / 64;                       // 64 nodes per 256-thr block
    agg_kernel<<<aggBlocks, 256, 0, stream>>>(hA, rowstartR, esort2, means, N);
    transform_kernel<<<tfBlocks, 256, 0, stream>>>(
        hA, means, w1root, w1rel, b1, hB, batch, linw, inv_cnt, out, N, 0);
    agg_kernel<<<aggBlocks, 256, 0, stream>>>(hB, rowstartR, esort2, means, N);
    transform_kernel<<<tfBlocks, 256, 0, stream>>>(
        hB, means, w2root, w2rel, b2, hA, batch, linw, inv_cnt, out, N, 1);
}